// Round 1
// baseline (4508.022 us; speedup 1.0000x reference)
//
#include <hip/hip_runtime.h>

// GIN regressor: 3x (aggregate + MLP) + pool + head, f32 throughout.
// Linearity trick: (h + agg(h)) @ wa == h@wa + agg(h@wa)  -> aggregate in
// 64-dim transformed space; fuse layer-MLP-2nd-matmul with next layer's 1st.

__global__ __launch_bounds__(256) void k_in(const float* __restrict__ x,
                                            const float* __restrict__ w,
                                            float* __restrict__ A, int n) {
  int i = blockIdx.x * 256 + threadIdx.x;
  if (i >= n) return;
  const float4* xr = (const float4*)(x + (size_t)i * 128);
  float acc[64];
#pragma unroll
  for (int j = 0; j < 64; ++j) acc[j] = 0.f;
#pragma unroll 2
  for (int k4 = 0; k4 < 32; ++k4) {
    float4 xv = xr[k4];
    const float* wr = w + k4 * 256;
#pragma unroll
    for (int kk = 0; kk < 4; ++kk) {
      float xs = (&xv.x)[kk];
#pragma unroll
      for (int j = 0; j < 64; ++j) acc[j] = fmaf(xs, wr[kk * 64 + j], acc[j]);
    }
  }
  float4* Ar = (float4*)(A + (size_t)i * 64);
#pragma unroll
  for (int j = 0; j < 16; ++j)
    Ar[j] = make_float4(acc[4 * j], acc[4 * j + 1], acc[4 * j + 2], acc[4 * j + 3]);
}

// B[dst] += A[src] over all edges. 16 threads/edge, float4 each.
__global__ __launch_bounds__(256) void k_agg(const int* __restrict__ ei,
                                             const float* __restrict__ A,
                                             float* __restrict__ B, int ne) {
  long t = (long)blockIdx.x * 256 + threadIdx.x;
  int e = (int)(t >> 4);
  if (e >= ne) return;
  int f4 = ((int)t & 15) * 4;
  int s = ei[e];
  int d = ei[ne + e];
  float4 v = *(const float4*)(A + (size_t)s * 64 + f4);
  float* dp = B + (size_t)d * 64 + f4;
  unsafeAtomicAdd(dp + 0, v.x);
  unsafeAtomicAdd(dp + 1, v.y);
  unsafeAtomicAdd(dp + 2, v.z);
  unsafeAtomicAdd(dp + 3, v.w);
}

// A <- relu(relu(A + B + ba) @ wb + bb) @ wn ; B <- 0  (in-place per-row safe)
__global__ __launch_bounds__(256) void k_layer(float* __restrict__ A,
                                               float* __restrict__ B,
                                               const float* __restrict__ ba,
                                               const float* __restrict__ wb,
                                               const float* __restrict__ bb,
                                               const float* __restrict__ wn,
                                               int n) {
  int i = blockIdx.x * 256 + threadIdx.x;
  if (i >= n) return;
  float4* Ar = (float4*)(A + (size_t)i * 64);
  float4* Br = (float4*)(B + (size_t)i * 64);
  float u[64];
#pragma unroll
  for (int k4 = 0; k4 < 16; ++k4) {
    float4 a = Ar[k4];
    float4 b = Br[k4];
    u[4 * k4 + 0] = fmaxf(a.x + b.x + ba[4 * k4 + 0], 0.f);
    u[4 * k4 + 1] = fmaxf(a.y + b.y + ba[4 * k4 + 1], 0.f);
    u[4 * k4 + 2] = fmaxf(a.z + b.z + ba[4 * k4 + 2], 0.f);
    u[4 * k4 + 3] = fmaxf(a.w + b.w + ba[4 * k4 + 3], 0.f);
    Br[k4] = make_float4(0.f, 0.f, 0.f, 0.f);
  }
  float v[64];
#pragma unroll
  for (int j = 0; j < 64; ++j) v[j] = bb[j];
#pragma unroll 4
  for (int k = 0; k < 64; ++k) {
    float us = u[k];
    const float* wr = wb + k * 64;
#pragma unroll
    for (int j = 0; j < 64; ++j) v[j] = fmaf(us, wr[j], v[j]);
  }
#pragma unroll
  for (int j = 0; j < 64; ++j) v[j] = fmaxf(v[j], 0.f);
  float acc[64];
#pragma unroll
  for (int j = 0; j < 64; ++j) acc[j] = 0.f;
#pragma unroll 4
  for (int k = 0; k < 64; ++k) {
    float vs = v[k];
    const float* wr = wn + k * 64;
#pragma unroll
    for (int j = 0; j < 64; ++j) acc[j] = fmaf(vs, wr[j], acc[j]);
  }
#pragma unroll
  for (int j = 0; j < 16; ++j)
    Ar[j] = make_float4(acc[4 * j], acc[4 * j + 1], acc[4 * j + 2], acc[4 * j + 3]);
}

// Final layer: h3 = relu(relu(A+B+ba)@wb+bb), then pool into P via LDS
// transpose (XOR swizzle, conflict-free) + sorted-batch run-length scan.
__global__ __launch_bounds__(256) void k_final(const float* __restrict__ A,
                                               const float* __restrict__ B,
                                               const float* __restrict__ ba,
                                               const float* __restrict__ wb,
                                               const float* __restrict__ bb,
                                               const int* __restrict__ batch,
                                               float* __restrict__ P, int n) {
  __shared__ float sh[64 * 256];  // 64 KB
  int tid = threadIdx.x;
  int i = blockIdx.x * 256 + tid;
  float v[64];
  if (i < n) {
    const float4* Ar = (const float4*)(A + (size_t)i * 64);
    const float4* Br = (const float4*)(B + (size_t)i * 64);
    float u[64];
#pragma unroll
    for (int k4 = 0; k4 < 16; ++k4) {
      float4 a = Ar[k4];
      float4 b = Br[k4];
      u[4 * k4 + 0] = fmaxf(a.x + b.x + ba[4 * k4 + 0], 0.f);
      u[4 * k4 + 1] = fmaxf(a.y + b.y + ba[4 * k4 + 1], 0.f);
      u[4 * k4 + 2] = fmaxf(a.z + b.z + ba[4 * k4 + 2], 0.f);
      u[4 * k4 + 3] = fmaxf(a.w + b.w + ba[4 * k4 + 3], 0.f);
    }
#pragma unroll
    for (int j = 0; j < 64; ++j) v[j] = bb[j];
#pragma unroll 4
    for (int k = 0; k < 64; ++k) {
      float us = u[k];
      const float* wr = wb + k * 64;
#pragma unroll
      for (int j = 0; j < 64; ++j) v[j] = fmaf(us, wr[j], v[j]);
    }
#pragma unroll
    for (int j = 0; j < 64; ++j) v[j] = fmaxf(v[j], 0.f);
  } else {
#pragma unroll
    for (int j = 0; j < 64; ++j) v[j] = 0.f;
  }
  // store transposed: (node tid, feat j) at sh[j*256 + (tid&~63) + ((tid&63)^j)]
  int hi = tid & ~63, lo = tid & 63;
#pragma unroll
  for (int j = 0; j < 64; ++j) sh[j * 256 + hi + (lo ^ j)] = v[j];
  __syncthreads();
  int f = tid & 63, q = tid >> 6;  // wave-uniform q; f = lane
  int base = blockIdx.x * 256 + q * 64;
  float run = 0.f;
  int cur = -1;
  for (int k = 0; k < 64; ++k) {
    int node = base + k;
    int g = (node < n) ? batch[node] : -1;  // wave-uniform
    float val = sh[f * 256 + q * 64 + (k ^ f)];
    if (g != cur) {
      if (cur >= 0) unsafeAtomicAdd(&P[(size_t)cur * 64 + f], run);
      run = 0.f;
      cur = g;
    }
    run += val;
  }
  if (cur >= 0) unsafeAtomicAdd(&P[(size_t)cur * 64 + f], run);
}

__global__ __launch_bounds__(256) void k_head(const float* __restrict__ P,
                                              const float* __restrict__ w1,
                                              const float* __restrict__ b1,
                                              const float* __restrict__ w2,
                                              const float* __restrict__ b2,
                                              float* __restrict__ out, int ng) {
  int g = blockIdx.x * 256 + threadIdx.x;
  if (g >= ng) return;
  const float4* Pr = (const float4*)(P + (size_t)g * 64);
  float p[64];
#pragma unroll
  for (int k4 = 0; k4 < 16; ++k4) {
    float4 a = Pr[k4];
    p[4 * k4 + 0] = a.x; p[4 * k4 + 1] = a.y;
    p[4 * k4 + 2] = a.z; p[4 * k4 + 3] = a.w;
  }
  float t[64];
#pragma unroll
  for (int j = 0; j < 64; ++j) t[j] = b1[j];
#pragma unroll 4
  for (int k = 0; k < 64; ++k) {
    float ps = p[k];
    const float* wr = w1 + k * 64;
#pragma unroll
    for (int j = 0; j < 64; ++j) t[j] = fmaf(ps, wr[j], t[j]);
  }
  float o = b2[0];
#pragma unroll
  for (int j = 0; j < 64; ++j) o = fmaf(fmaxf(t[j], 0.f), w2[j], o);
  out[g] = o;
}

extern "C" void kernel_launch(void* const* d_in, const int* in_sizes, int n_in,
                              void* d_out, int out_size, void* d_ws, size_t ws_size,
                              hipStream_t stream) {
  const float* x   = (const float*)d_in[0];
  const int*   ei  = (const int*)d_in[1];
  const int*   bat = (const int*)d_in[2];
  const float* w0a = (const float*)d_in[3];
  const float* b0a = (const float*)d_in[4];
  const float* w0b = (const float*)d_in[5];
  const float* b0b = (const float*)d_in[6];
  const float* w1a = (const float*)d_in[7];
  const float* b1a = (const float*)d_in[8];
  const float* w1b = (const float*)d_in[9];
  const float* b1b = (const float*)d_in[10];
  const float* w2a = (const float*)d_in[11];
  const float* b2a = (const float*)d_in[12];
  const float* w2b = (const float*)d_in[13];
  const float* b2b = (const float*)d_in[14];
  const float* wh1 = (const float*)d_in[15];
  const float* bh1 = (const float*)d_in[16];
  const float* wh2 = (const float*)d_in[17];
  const float* bh2 = (const float*)d_in[18];
  float* out = (float*)d_out;

  const int N = in_sizes[0] / 128;   // 500000
  const int E = in_sizes[1] / 2;     // 1250000
  const int G = out_size;            // 16384

  float* A = (float*)d_ws;                 // N*64 floats
  float* B = A + (size_t)N * 64;           // N*64 floats
  float* P = B + (size_t)N * 64;           // G*64 floats

  hipMemsetAsync(B, 0, (size_t)N * 64 * sizeof(float), stream);
  hipMemsetAsync(P, 0, (size_t)G * 64 * sizeof(float), stream);

  int nb = (N + 255) / 256;
  int eb = (int)(((long)E * 16 + 255) / 256);
  int gb = (G + 255) / 256;

  k_in<<<nb, 256, 0, stream>>>(x, w0a, A, N);
  k_agg<<<eb, 256, 0, stream>>>(ei, A, B, E);
  k_layer<<<nb, 256, 0, stream>>>(A, B, b0a, w0b, b0b, w1a, N);
  k_agg<<<eb, 256, 0, stream>>>(ei, A, B, E);
  k_layer<<<nb, 256, 0, stream>>>(A, B, b1a, w1b, b1b, w2a, N);
  k_agg<<<eb, 256, 0, stream>>>(ei, A, B, E);
  k_final<<<nb, 256, 0, stream>>>(A, B, b2a, w2b, b2b, bat, P, N);
  k_head<<<gb, 256, 0, stream>>>(P, wh1, bh1, wh2, bh2, out, G);
}

// Round 2
// 2102.558 us; speedup vs baseline: 2.1441x; 2.1441x over previous
//
#include <hip/hip_runtime.h>

// GIN regressor: 3x (aggregate + MLP) + pool + head, f32 throughout.
// Linearity trick: (h + agg(h)) @ wa == h@wa + agg(h@wa)  -> aggregate in
// 64-dim transformed space; fuse layer-MLP-2nd-matmul with next layer's 1st.
// R2: scatter-atomic aggregation (1.25 GB writeback/layer, atomic-bound)
// replaced by per-launch CSR build + gather-reduce (zero f32 atomics).

// ---------------- CSR build ----------------

__global__ __launch_bounds__(256) void k_deg(const int* __restrict__ ei,
                                             int* __restrict__ deg, int ne) {
  int e = blockIdx.x * 256 + threadIdx.x;
  if (e >= ne) return;
  atomicAdd(&deg[ei[ne + e]], 1);
}

// block-level inclusive scan (1024/block) -> exclusive per-elem + block sums
__global__ __launch_bounds__(1024) void k_scan1(const int* __restrict__ deg,
                                                int* __restrict__ rp,
                                                int* __restrict__ bsum, int n) {
  __shared__ int sh[1024];
  int tid = threadIdx.x;
  int i = blockIdx.x * 1024 + tid;
  int d = (i < n) ? deg[i] : 0;
  sh[tid] = d;
  __syncthreads();
  for (int off = 1; off < 1024; off <<= 1) {
    int v = (tid >= off) ? sh[tid - off] : 0;
    __syncthreads();
    sh[tid] += v;
    __syncthreads();
  }
  if (i < n) rp[i] = sh[tid] - d;
  if (tid == 1023) bsum[blockIdx.x] = sh[1023];
}

__global__ __launch_bounds__(512) void k_scan2(const int* __restrict__ bsum,
                                               int* __restrict__ boff, int nb) {
  __shared__ int sh[512];
  int tid = threadIdx.x;
  int d = (tid < nb) ? bsum[tid] : 0;
  sh[tid] = d;
  __syncthreads();
  for (int off = 1; off < 512; off <<= 1) {
    int v = (tid >= off) ? sh[tid - off] : 0;
    __syncthreads();
    sh[tid] += v;
    __syncthreads();
  }
  if (tid < nb) boff[tid] = sh[tid] - d;
}

__global__ __launch_bounds__(256) void k_scan3(int* __restrict__ rp,
                                               const int* __restrict__ boff, int n) {
  int i = blockIdx.x * 256 + threadIdx.x;
  if (i >= n) return;
  rp[i] += boff[i >> 10];
}

__global__ __launch_bounds__(256) void k_fill(const int* __restrict__ ei,
                                              const int* __restrict__ rp,
                                              int* __restrict__ cur,
                                              int* __restrict__ csr, int ne) {
  int e = blockIdx.x * 256 + threadIdx.x;
  if (e >= ne) return;
  int s = ei[e];
  int d = ei[ne + e];
  int pos = atomicAdd(&cur[d], 1);
  csr[rp[d] + pos] = s;
}

// ---------------- compute ----------------

__global__ __launch_bounds__(256) void k_in(const float* __restrict__ x,
                                            const float* __restrict__ w,
                                            float* __restrict__ A, int n) {
  int i = blockIdx.x * 256 + threadIdx.x;
  if (i >= n) return;
  const float4* xr = (const float4*)(x + (size_t)i * 128);
  float acc[64];
#pragma unroll
  for (int j = 0; j < 64; ++j) acc[j] = 0.f;
#pragma unroll 2
  for (int k4 = 0; k4 < 32; ++k4) {
    float4 xv = xr[k4];
    const float* wr = w + k4 * 256;
#pragma unroll
    for (int kk = 0; kk < 4; ++kk) {
      float xs = (&xv.x)[kk];
#pragma unroll
      for (int j = 0; j < 64; ++j) acc[j] = fmaf(xs, wr[kk * 64 + j], acc[j]);
    }
  }
  float4* Ar = (float4*)(A + (size_t)i * 64);
#pragma unroll
  for (int j = 0; j < 16; ++j)
    Ar[j] = make_float4(acc[4 * j], acc[4 * j + 1], acc[4 * j + 2], acc[4 * j + 3]);
}

// B[i] = sum_{j in in-neighbors(i)} A[j].  16 threads/node, float4/thread.
__global__ __launch_bounds__(256) void k_gather(const int* __restrict__ rp,
                                                const int* __restrict__ deg,
                                                const int* __restrict__ csr,
                                                const float* __restrict__ A,
                                                float* __restrict__ B, int n) {
  long t = (long)blockIdx.x * 256 + threadIdx.x;
  int i = (int)(t >> 4);
  if (i >= n) return;
  int sl = ((int)t & 15) * 4;
  int start = rp[i];
  int d = deg[i];
  float4 acc = make_float4(0.f, 0.f, 0.f, 0.f);
  for (int e = 0; e < d; ++e) {
    int s = csr[start + e];
    float4 v = *(const float4*)(A + (size_t)s * 64 + sl);
    acc.x += v.x; acc.y += v.y; acc.z += v.z; acc.w += v.w;
  }
  *(float4*)(B + (size_t)i * 64 + sl) = acc;
}

// A <- relu(relu(A + B + ba) @ wb + bb) @ wn   (in-place per-row safe)
__global__ __launch_bounds__(256) void k_layer(float* __restrict__ A,
                                               const float* __restrict__ B,
                                               const float* __restrict__ ba,
                                               const float* __restrict__ wb,
                                               const float* __restrict__ bb,
                                               const float* __restrict__ wn,
                                               int n) {
  int i = blockIdx.x * 256 + threadIdx.x;
  if (i >= n) return;
  float4* Ar = (float4*)(A + (size_t)i * 64);
  const float4* Br = (const float4*)(B + (size_t)i * 64);
  float v[64];
#pragma unroll
  for (int j = 0; j < 64; ++j) v[j] = bb[j];
#pragma unroll
  for (int k4 = 0; k4 < 16; ++k4) {
    float4 a = Ar[k4];
    float4 b = Br[k4];
#pragma unroll
    for (int kk = 0; kk < 4; ++kk) {
      int k = k4 * 4 + kk;
      float u = fmaxf((&a.x)[kk] + (&b.x)[kk] + ba[k], 0.f);
      const float* wr = wb + k * 64;
#pragma unroll
      for (int j = 0; j < 64; ++j) v[j] = fmaf(u, wr[j], v[j]);
    }
  }
  float acc[64];
#pragma unroll
  for (int j = 0; j < 64; ++j) acc[j] = 0.f;
#pragma unroll 4
  for (int k = 0; k < 64; ++k) {
    float vs = fmaxf(v[k], 0.f);
    const float* wr = wn + k * 64;
#pragma unroll
    for (int j = 0; j < 64; ++j) acc[j] = fmaf(vs, wr[j], acc[j]);
  }
#pragma unroll
  for (int j = 0; j < 16; ++j)
    Ar[j] = make_float4(acc[4 * j], acc[4 * j + 1], acc[4 * j + 2], acc[4 * j + 3]);
}

// Final layer: h3 = relu(relu(A+B+ba)@wb+bb), then pool into P via LDS
// transpose (XOR swizzle, conflict-free) + sorted-batch run-length scan.
__global__ __launch_bounds__(256) void k_final(const float* __restrict__ A,
                                               const float* __restrict__ B,
                                               const float* __restrict__ ba,
                                               const float* __restrict__ wb,
                                               const float* __restrict__ bb,
                                               const int* __restrict__ batch,
                                               float* __restrict__ P, int n) {
  __shared__ float sh[64 * 256];  // 64 KB
  int tid = threadIdx.x;
  int i = blockIdx.x * 256 + tid;
  float v[64];
  if (i < n) {
    const float4* Ar = (const float4*)(A + (size_t)i * 64);
    const float4* Br = (const float4*)(B + (size_t)i * 64);
#pragma unroll
    for (int j = 0; j < 64; ++j) v[j] = bb[j];
#pragma unroll
    for (int k4 = 0; k4 < 16; ++k4) {
      float4 a = Ar[k4];
      float4 b = Br[k4];
#pragma unroll
      for (int kk = 0; kk < 4; ++kk) {
        int k = k4 * 4 + kk;
        float u = fmaxf((&a.x)[kk] + (&b.x)[kk] + ba[k], 0.f);
        const float* wr = wb + k * 64;
#pragma unroll
        for (int j = 0; j < 64; ++j) v[j] = fmaf(u, wr[j], v[j]);
      }
    }
#pragma unroll
    for (int j = 0; j < 64; ++j) v[j] = fmaxf(v[j], 0.f);
  } else {
#pragma unroll
    for (int j = 0; j < 64; ++j) v[j] = 0.f;
  }
  // store transposed: (node tid, feat j) at sh[j*256 + (tid&~63) + ((tid&63)^j)]
  int hi = tid & ~63, lo = tid & 63;
#pragma unroll
  for (int j = 0; j < 64; ++j) sh[j * 256 + hi + (lo ^ j)] = v[j];
  __syncthreads();
  int f = tid & 63, q = tid >> 6;  // wave-uniform q; f = lane
  int base = blockIdx.x * 256 + q * 64;
  float run = 0.f;
  int cur = -1;
  for (int k = 0; k < 64; ++k) {
    int node = base + k;
    int g = (node < n) ? batch[node] : -1;  // wave-uniform
    float val = sh[f * 256 + q * 64 + (k ^ f)];
    if (g != cur) {
      if (cur >= 0) unsafeAtomicAdd(&P[(size_t)cur * 64 + f], run);
      run = 0.f;
      cur = g;
    }
    run += val;
  }
  if (cur >= 0) unsafeAtomicAdd(&P[(size_t)cur * 64 + f], run);
}

__global__ __launch_bounds__(256) void k_head(const float* __restrict__ P,
                                              const float* __restrict__ w1,
                                              const float* __restrict__ b1,
                                              const float* __restrict__ w2,
                                              const float* __restrict__ b2,
                                              float* __restrict__ out, int ng) {
  int g = blockIdx.x * 256 + threadIdx.x;
  if (g >= ng) return;
  const float4* Pr = (const float4*)(P + (size_t)g * 64);
  float t[64];
#pragma unroll
  for (int j = 0; j < 64; ++j) t[j] = b1[j];
#pragma unroll
  for (int k4 = 0; k4 < 16; ++k4) {
    float4 a = Pr[k4];
#pragma unroll
    for (int kk = 0; kk < 4; ++kk) {
      float ps = (&a.x)[kk];
      const float* wr = w1 + (k4 * 4 + kk) * 64;
#pragma unroll
      for (int j = 0; j < 64; ++j) t[j] = fmaf(ps, wr[j], t[j]);
    }
  }
  float o = b2[0];
#pragma unroll
  for (int j = 0; j < 64; ++j) o = fmaf(fmaxf(t[j], 0.f), w2[j], o);
  out[g] = o;
}

extern "C" void kernel_launch(void* const* d_in, const int* in_sizes, int n_in,
                              void* d_out, int out_size, void* d_ws, size_t ws_size,
                              hipStream_t stream) {
  const float* x   = (const float*)d_in[0];
  const int*   ei  = (const int*)d_in[1];
  const int*   bat = (const int*)d_in[2];
  const float* w0a = (const float*)d_in[3];
  const float* b0a = (const float*)d_in[4];
  const float* w0b = (const float*)d_in[5];
  const float* b0b = (const float*)d_in[6];
  const float* w1a = (const float*)d_in[7];
  const float* b1a = (const float*)d_in[8];
  const float* w1b = (const float*)d_in[9];
  const float* b1b = (const float*)d_in[10];
  const float* w2a = (const float*)d_in[11];
  const float* b2a = (const float*)d_in[12];
  const float* w2b = (const float*)d_in[13];
  const float* b2b = (const float*)d_in[14];
  const float* wh1 = (const float*)d_in[15];
  const float* bh1 = (const float*)d_in[16];
  const float* wh2 = (const float*)d_in[17];
  const float* bh2 = (const float*)d_in[18];
  float* out = (float*)d_out;

  const int N = in_sizes[0] / 128;   // 500000
  const int E = in_sizes[1] / 2;     // 1250000
  const int G = out_size;            // 16384

  char* w = (char*)d_ws;
  float* A    = (float*)w;  w += (size_t)N * 64 * sizeof(float);   // 128 MB
  float* B    = (float*)w;  w += (size_t)N * 64 * sizeof(float);   // 128 MB
  float* P    = (float*)w;  w += (size_t)G * 64 * sizeof(float);   // 4 MB
  int*   deg  = (int*)w;    w += (size_t)N * sizeof(int);          // 2 MB
  int*   cur  = (int*)w;    w += (size_t)N * sizeof(int);          // 2 MB
  int*   rp   = (int*)w;    w += (size_t)(N + 1) * sizeof(int);    // 2 MB
  int*   bsum = (int*)w;    w += 1024 * sizeof(int);
  int*   boff = (int*)w;    w += 1024 * sizeof(int);
  int*   csr  = (int*)w;    w += (size_t)E * sizeof(int);          // 5 MB

  hipMemsetAsync(P, 0, (size_t)G * 64 * sizeof(float), stream);
  hipMemsetAsync(deg, 0, (size_t)N * sizeof(int), stream);
  hipMemsetAsync(cur, 0, (size_t)N * sizeof(int), stream);

  int nb = (N + 255) / 256;
  int ebs = (E + 255) / 256;
  int ngb = (int)(((long)N * 16 + 255) / 256);
  int gb = (G + 255) / 256;
  int nb1 = (N + 1023) / 1024;  // scan blocks (489)

  // CSR build (same every call; edges are restored pristine before each launch)
  k_deg<<<ebs, 256, 0, stream>>>(ei, deg, E);
  k_scan1<<<nb1, 1024, 0, stream>>>(deg, rp, bsum, N);
  k_scan2<<<1, 512, 0, stream>>>(bsum, boff, nb1);
  k_scan3<<<nb, 256, 0, stream>>>(rp, boff, N);
  k_fill<<<ebs, 256, 0, stream>>>(ei, rp, cur, csr, E);

  k_in<<<nb, 256, 0, stream>>>(x, w0a, A, N);
  k_gather<<<ngb, 256, 0, stream>>>(rp, deg, csr, A, B, N);
  k_layer<<<nb, 256, 0, stream>>>(A, B, b0a, w0b, b0b, w1a, N);
  k_gather<<<ngb, 256, 0, stream>>>(rp, deg, csr, A, B, N);
  k_layer<<<nb, 256, 0, stream>>>(A, B, b1a, w1b, b1b, w2a, N);
  k_gather<<<ngb, 256, 0, stream>>>(rp, deg, csr, A, B, N);
  k_final<<<nb, 256, 0, stream>>>(A, B, b2a, w2b, b2b, bat, P, N);
  k_head<<<gb, 256, 0, stream>>>(P, wh1, bh1, wh2, bh2, out, G);
}

// Round 3
// 1598.905 us; speedup vs baseline: 2.8194x; 1.3150x over previous
//
#include <hip/hip_runtime.h>

// GIN regressor: 3x (aggregate + MLP) + pool + head, f32 throughout.
// Linearity trick: (h + agg(h)) @ wa == h@wa + agg(h@wa)  -> aggregate in
// 64-dim transformed space; fuse layer-MLP-2nd-matmul with next layer's 1st.
// R2: CSR build + gather-reduce (zero f32 atomics).
// R3: k_layer second GEMM was `#pragma unroll 4` -> v[k] dynamic index ->
// scratch spill (VGPR=72, 1.7 GB HBM writes). Full unroll -> registers.

// ---------------- CSR build ----------------

__global__ __launch_bounds__(256) void k_deg(const int* __restrict__ ei,
                                             int* __restrict__ deg, int ne) {
  int e = blockIdx.x * 256 + threadIdx.x;
  if (e >= ne) return;
  atomicAdd(&deg[ei[ne + e]], 1);
}

// block-level inclusive scan (1024/block) -> exclusive per-elem + block sums
__global__ __launch_bounds__(1024) void k_scan1(const int* __restrict__ deg,
                                                int* __restrict__ rp,
                                                int* __restrict__ bsum, int n) {
  __shared__ int sh[1024];
  int tid = threadIdx.x;
  int i = blockIdx.x * 1024 + tid;
  int d = (i < n) ? deg[i] : 0;
  sh[tid] = d;
  __syncthreads();
  for (int off = 1; off < 1024; off <<= 1) {
    int v = (tid >= off) ? sh[tid - off] : 0;
    __syncthreads();
    sh[tid] += v;
    __syncthreads();
  }
  if (i < n) rp[i] = sh[tid] - d;
  if (tid == 1023) bsum[blockIdx.x] = sh[1023];
}

__global__ __launch_bounds__(512) void k_scan2(const int* __restrict__ bsum,
                                               int* __restrict__ boff, int nb) {
  __shared__ int sh[512];
  int tid = threadIdx.x;
  int d = (tid < nb) ? bsum[tid] : 0;
  sh[tid] = d;
  __syncthreads();
  for (int off = 1; off < 512; off <<= 1) {
    int v = (tid >= off) ? sh[tid - off] : 0;
    __syncthreads();
    sh[tid] += v;
    __syncthreads();
  }
  if (tid < nb) boff[tid] = sh[tid] - d;
}

__global__ __launch_bounds__(256) void k_scan3(int* __restrict__ rp,
                                               const int* __restrict__ boff, int n) {
  int i = blockIdx.x * 256 + threadIdx.x;
  if (i >= n) return;
  rp[i] += boff[i >> 10];
}

__global__ __launch_bounds__(256) void k_fill(const int* __restrict__ ei,
                                              const int* __restrict__ rp,
                                              int* __restrict__ cur,
                                              int* __restrict__ csr, int ne) {
  int e = blockIdx.x * 256 + threadIdx.x;
  if (e >= ne) return;
  int s = ei[e];
  int d = ei[ne + e];
  int pos = atomicAdd(&cur[d], 1);
  csr[rp[d] + pos] = s;
}

// ---------------- compute ----------------

__global__ __launch_bounds__(256) void k_in(const float* __restrict__ x,
                                            const float* __restrict__ w,
                                            float* __restrict__ A, int n) {
  int i = blockIdx.x * 256 + threadIdx.x;
  if (i >= n) return;
  const float4* xr = (const float4*)(x + (size_t)i * 128);
  float acc[64];
#pragma unroll
  for (int j = 0; j < 64; ++j) acc[j] = 0.f;
#pragma unroll 2
  for (int k4 = 0; k4 < 32; ++k4) {
    float4 xv = xr[k4];
    const float* wr = w + k4 * 256;
#pragma unroll
    for (int kk = 0; kk < 4; ++kk) {
      float xs = (&xv.x)[kk];
#pragma unroll
      for (int j = 0; j < 64; ++j) acc[j] = fmaf(xs, wr[kk * 64 + j], acc[j]);
    }
  }
  float4* Ar = (float4*)(A + (size_t)i * 64);
#pragma unroll
  for (int j = 0; j < 16; ++j)
    Ar[j] = make_float4(acc[4 * j], acc[4 * j + 1], acc[4 * j + 2], acc[4 * j + 3]);
}

// B[i] = sum_{j in in-neighbors(i)} A[j].  16 threads/node, float4/thread.
__global__ __launch_bounds__(256) void k_gather(const int* __restrict__ rp,
                                                const int* __restrict__ deg,
                                                const int* __restrict__ csr,
                                                const float* __restrict__ A,
                                                float* __restrict__ B, int n) {
  long t = (long)blockIdx.x * 256 + threadIdx.x;
  int i = (int)(t >> 4);
  if (i >= n) return;
  int sl = ((int)t & 15) * 4;
  int start = rp[i];
  int d = deg[i];
  float4 acc = make_float4(0.f, 0.f, 0.f, 0.f);
  for (int e = 0; e < d; ++e) {
    int s = csr[start + e];
    float4 v = *(const float4*)(A + (size_t)s * 64 + sl);
    acc.x += v.x; acc.y += v.y; acc.z += v.z; acc.w += v.w;
  }
  *(float4*)(B + (size_t)i * 64 + sl) = acc;
}

// A <- relu(relu(A + B + ba) @ wb + bb) @ wn   (in-place per-row safe)
__global__ __launch_bounds__(256) void k_layer(float* __restrict__ A,
                                               const float* __restrict__ B,
                                               const float* __restrict__ ba,
                                               const float* __restrict__ wb,
                                               const float* __restrict__ bb,
                                               const float* __restrict__ wn,
                                               int n) {
  int i = blockIdx.x * 256 + threadIdx.x;
  if (i >= n) return;
  float4* Ar = (float4*)(A + (size_t)i * 64);
  const float4* Br = (const float4*)(B + (size_t)i * 64);
  float v[64];
#pragma unroll
  for (int j = 0; j < 64; ++j) v[j] = bb[j];
#pragma unroll
  for (int k4 = 0; k4 < 16; ++k4) {
    float4 a = Ar[k4];
    float4 b = Br[k4];
#pragma unroll
    for (int kk = 0; kk < 4; ++kk) {
      int k = k4 * 4 + kk;
      float u = fmaxf((&a.x)[kk] + (&b.x)[kk] + ba[k], 0.f);
      const float* wr = wb + k * 64;
#pragma unroll
      for (int j = 0; j < 64; ++j) v[j] = fmaf(u, wr[j], v[j]);
    }
  }
  float acc[64];
#pragma unroll
  for (int j = 0; j < 64; ++j) acc[j] = 0.f;
#pragma unroll
  for (int k = 0; k < 64; ++k) {   // FULL unroll: v[k] must be constant-indexed
    float vs = fmaxf(v[k], 0.f);
    const float* wr = wn + k * 64;
#pragma unroll
    for (int j = 0; j < 64; ++j) acc[j] = fmaf(vs, wr[j], acc[j]);
  }
#pragma unroll
  for (int j = 0; j < 16; ++j)
    Ar[j] = make_float4(acc[4 * j], acc[4 * j + 1], acc[4 * j + 2], acc[4 * j + 3]);
}

// Final layer: h3 = relu(relu(A+B+ba)@wb+bb), then pool into P via LDS
// transpose (XOR swizzle, conflict-free) + sorted-batch run-length scan.
__global__ __launch_bounds__(256) void k_final(const float* __restrict__ A,
                                               const float* __restrict__ B,
                                               const float* __restrict__ ba,
                                               const float* __restrict__ wb,
                                               const float* __restrict__ bb,
                                               const int* __restrict__ batch,
                                               float* __restrict__ P, int n) {
  __shared__ float sh[64 * 256];  // 64 KB
  int tid = threadIdx.x;
  int i = blockIdx.x * 256 + tid;
  float v[64];
  if (i < n) {
    const float4* Ar = (const float4*)(A + (size_t)i * 64);
    const float4* Br = (const float4*)(B + (size_t)i * 64);
#pragma unroll
    for (int j = 0; j < 64; ++j) v[j] = bb[j];
#pragma unroll
    for (int k4 = 0; k4 < 16; ++k4) {
      float4 a = Ar[k4];
      float4 b = Br[k4];
#pragma unroll
      for (int kk = 0; kk < 4; ++kk) {
        int k = k4 * 4 + kk;
        float u = fmaxf((&a.x)[kk] + (&b.x)[kk] + ba[k], 0.f);
        const float* wr = wb + k * 64;
#pragma unroll
        for (int j = 0; j < 64; ++j) v[j] = fmaf(u, wr[j], v[j]);
      }
    }
#pragma unroll
    for (int j = 0; j < 64; ++j) v[j] = fmaxf(v[j], 0.f);
  } else {
#pragma unroll
    for (int j = 0; j < 64; ++j) v[j] = 0.f;
  }
  // store transposed: (node tid, feat j) at sh[j*256 + (tid&~63) + ((tid&63)^j)]
  int hi = tid & ~63, lo = tid & 63;
#pragma unroll
  for (int j = 0; j < 64; ++j) sh[j * 256 + hi + (lo ^ j)] = v[j];
  __syncthreads();
  int f = tid & 63, q = tid >> 6;  // wave-uniform q; f = lane
  int base = blockIdx.x * 256 + q * 64;
  float run = 0.f;
  int cur = -1;
  for (int k = 0; k < 64; ++k) {
    int node = base + k;
    int g = (node < n) ? batch[node] : -1;  // wave-uniform
    float val = sh[f * 256 + q * 64 + (k ^ f)];
    if (g != cur) {
      if (cur >= 0) unsafeAtomicAdd(&P[(size_t)cur * 64 + f], run);
      run = 0.f;
      cur = g;
    }
    run += val;
  }
  if (cur >= 0) unsafeAtomicAdd(&P[(size_t)cur * 64 + f], run);
}

__global__ __launch_bounds__(256) void k_head(const float* __restrict__ P,
                                              const float* __restrict__ w1,
                                              const float* __restrict__ b1,
                                              const float* __restrict__ w2,
                                              const float* __restrict__ b2,
                                              float* __restrict__ out, int ng) {
  int g = blockIdx.x * 256 + threadIdx.x;
  if (g >= ng) return;
  const float4* Pr = (const float4*)(P + (size_t)g * 64);
  float t[64];
#pragma unroll
  for (int j = 0; j < 64; ++j) t[j] = b1[j];
#pragma unroll
  for (int k4 = 0; k4 < 16; ++k4) {
    float4 a = Pr[k4];
#pragma unroll
    for (int kk = 0; kk < 4; ++kk) {
      float ps = (&a.x)[kk];
      const float* wr = w1 + (k4 * 4 + kk) * 64;
#pragma unroll
      for (int j = 0; j < 64; ++j) t[j] = fmaf(ps, wr[j], t[j]);
    }
  }
  float o = b2[0];
#pragma unroll
  for (int j = 0; j < 64; ++j) o = fmaf(fmaxf(t[j], 0.f), w2[j], o);
  out[g] = o;
}

extern "C" void kernel_launch(void* const* d_in, const int* in_sizes, int n_in,
                              void* d_out, int out_size, void* d_ws, size_t ws_size,
                              hipStream_t stream) {
  const float* x   = (const float*)d_in[0];
  const int*   ei  = (const int*)d_in[1];
  const int*   bat = (const int*)d_in[2];
  const float* w0a = (const float*)d_in[3];
  const float* b0a = (const float*)d_in[4];
  const float* w0b = (const float*)d_in[5];
  const float* b0b = (const float*)d_in[6];
  const float* w1a = (const float*)d_in[7];
  const float* b1a = (const float*)d_in[8];
  const float* w1b = (const float*)d_in[9];
  const float* b1b = (const float*)d_in[10];
  const float* w2a = (const float*)d_in[11];
  const float* b2a = (const float*)d_in[12];
  const float* w2b = (const float*)d_in[13];
  const float* b2b = (const float*)d_in[14];
  const float* wh1 = (const float*)d_in[15];
  const float* bh1 = (const float*)d_in[16];
  const float* wh2 = (const float*)d_in[17];
  const float* bh2 = (const float*)d_in[18];
  float* out = (float*)d_out;

  const int N = in_sizes[0] / 128;   // 500000
  const int E = in_sizes[1] / 2;     // 1250000
  const int G = out_size;            // 16384

  char* w = (char*)d_ws;
  float* A    = (float*)w;  w += (size_t)N * 64 * sizeof(float);   // 128 MB
  float* B    = (float*)w;  w += (size_t)N * 64 * sizeof(float);   // 128 MB
  float* P    = (float*)w;  w += (size_t)G * 64 * sizeof(float);   // 4 MB
  int*   deg  = (int*)w;    w += (size_t)N * sizeof(int);          // 2 MB
  int*   cur  = (int*)w;    w += (size_t)N * sizeof(int);          // 2 MB
  int*   rp   = (int*)w;    w += (size_t)(N + 1) * sizeof(int);    // 2 MB
  int*   bsum = (int*)w;    w += 1024 * sizeof(int);
  int*   boff = (int*)w;    w += 1024 * sizeof(int);
  int*   csr  = (int*)w;    w += (size_t)E * sizeof(int);          // 5 MB

  hipMemsetAsync(P, 0, (size_t)G * 64 * sizeof(float), stream);
  hipMemsetAsync(deg, 0, (size_t)N * sizeof(int), stream);
  hipMemsetAsync(cur, 0, (size_t)N * sizeof(int), stream);

  int nb = (N + 255) / 256;
  int ebs = (E + 255) / 256;
  int ngb = (int)(((long)N * 16 + 255) / 256);
  int gb = (G + 255) / 256;
  int nb1 = (N + 1023) / 1024;  // scan blocks (489)

  // CSR build (same every call; edges are restored pristine before each launch)
  k_deg<<<ebs, 256, 0, stream>>>(ei, deg, E);
  k_scan1<<<nb1, 1024, 0, stream>>>(deg, rp, bsum, N);
  k_scan2<<<1, 512, 0, stream>>>(bsum, boff, nb1);
  k_scan3<<<nb, 256, 0, stream>>>(rp, boff, N);
  k_fill<<<ebs, 256, 0, stream>>>(ei, rp, cur, csr, E);

  k_in<<<nb, 256, 0, stream>>>(x, w0a, A, N);
  k_gather<<<ngb, 256, 0, stream>>>(rp, deg, csr, A, B, N);
  k_layer<<<nb, 256, 0, stream>>>(A, B, b0a, w0b, b0b, w1a, N);
  k_gather<<<ngb, 256, 0, stream>>>(rp, deg, csr, A, B, N);
  k_layer<<<nb, 256, 0, stream>>>(A, B, b1a, w1b, b1b, w2a, N);
  k_gather<<<ngb, 256, 0, stream>>>(rp, deg, csr, A, B, N);
  k_final<<<nb, 256, 0, stream>>>(A, B, b2a, w2b, b2b, bat, P, N);
  k_head<<<gb, 256, 0, stream>>>(P, wh1, bh1, wh2, bh2, out, G);
}

// Round 5
// 1220.165 us; speedup vs baseline: 3.6946x; 1.3104x over previous
//
#include <hip/hip_runtime.h>

// GIN regressor: 3x (aggregate + MLP) + pool + head, f32 throughout.
// Linearity trick: (h + agg(h)) @ wa == h@wa + agg(h@wa)  -> aggregate in
// 64-dim transformed space; fuse layer-MLP-2nd-matmul with next layer's 1st.
// R2: CSR build + gather-reduce (zero f32 atomics).
// R3: full-unroll fixed scratch spill; but weights-via-s_load thrash the
//     16 KB scalar cache (32 KB stream/wave) -> 22% VALUBusy, latency-bound.
// R4: register-tiled LDS GEMM: block=128 nodes, thread-tile 4 nodes x 8
//     feats, u in LDS (stride 65 -> conflict-free), weights staged in LDS
//     (wave-broadcast b128 reads). Weights hit L2 once per block, not per wave.
// R5: identical to R4 — previous bench was an infra failure (container), not
//     a kernel failure; resubmitting for measurement.

// ---------------- CSR build ----------------

__global__ __launch_bounds__(256) void k_deg(const int* __restrict__ ei,
                                             int* __restrict__ deg, int ne) {
  int e = blockIdx.x * 256 + threadIdx.x;
  if (e >= ne) return;
  atomicAdd(&deg[ei[ne + e]], 1);
}

__global__ __launch_bounds__(1024) void k_scan1(const int* __restrict__ deg,
                                                int* __restrict__ rp,
                                                int* __restrict__ bsum, int n) {
  __shared__ int sh[1024];
  int tid = threadIdx.x;
  int i = blockIdx.x * 1024 + tid;
  int d = (i < n) ? deg[i] : 0;
  sh[tid] = d;
  __syncthreads();
  for (int off = 1; off < 1024; off <<= 1) {
    int v = (tid >= off) ? sh[tid - off] : 0;
    __syncthreads();
    sh[tid] += v;
    __syncthreads();
  }
  if (i < n) rp[i] = sh[tid] - d;
  if (tid == 1023) bsum[blockIdx.x] = sh[1023];
}

__global__ __launch_bounds__(512) void k_scan2(const int* __restrict__ bsum,
                                               int* __restrict__ boff, int nb) {
  __shared__ int sh[512];
  int tid = threadIdx.x;
  int d = (tid < nb) ? bsum[tid] : 0;
  sh[tid] = d;
  __syncthreads();
  for (int off = 1; off < 512; off <<= 1) {
    int v = (tid >= off) ? sh[tid - off] : 0;
    __syncthreads();
    sh[tid] += v;
    __syncthreads();
  }
  if (tid < nb) boff[tid] = sh[tid] - d;
}

__global__ __launch_bounds__(256) void k_scan3(int* __restrict__ rp,
                                               const int* __restrict__ boff, int n) {
  int i = blockIdx.x * 256 + threadIdx.x;
  if (i >= n) return;
  rp[i] += boff[i >> 10];
}

__global__ __launch_bounds__(256) void k_fill(const int* __restrict__ ei,
                                              const int* __restrict__ rp,
                                              int* __restrict__ cur,
                                              int* __restrict__ csr, int ne) {
  int e = blockIdx.x * 256 + threadIdx.x;
  if (e >= ne) return;
  int s = ei[e];
  int d = ei[ne + e];
  int pos = atomicAdd(&cur[d], 1);
  csr[rp[d] + pos] = s;
}

// ---------------- gather ----------------

__global__ __launch_bounds__(256) void k_gather(const int* __restrict__ rp,
                                                const int* __restrict__ deg,
                                                const int* __restrict__ csr,
                                                const float* __restrict__ A,
                                                float* __restrict__ B, int n) {
  long t = (long)blockIdx.x * 256 + threadIdx.x;
  int i = (int)(t >> 4);
  if (i >= n) return;
  int sl = ((int)t & 15) * 4;
  int start = rp[i];
  int d = deg[i];
  float4 acc = make_float4(0.f, 0.f, 0.f, 0.f);
  for (int e = 0; e < d; ++e) {
    int s = csr[start + e];
    float4 v = *(const float4*)(A + (size_t)s * 64 + sl);
    acc.x += v.x; acc.y += v.y; acc.z += v.z; acc.w += v.w;
  }
  *(float4*)(B + (size_t)i * 64 + sl) = acc;
}

// ---------------- tiled GEMM kernels ----------------
// Block = 128 nodes, 256 threads. Thread (ng = t&31, fg = t>>5) computes a
// 4-node (ng, ng+32, ng+64, ng+96) x 8-feat (fg*8..) tile.
// su: [128][65] f32 (stride 65 == 1 mod 32 -> conflict-free u[.][k] columns).
// sw: [64][64] staged weight; GEMM w-reads are wave-broadcast b128.

#define GEMM_TILE(SU, SW, ACC)                                              \
  {                                                                         \
    _Pragma("unroll 4") for (int k = 0; k < 64; ++k) {                      \
      float uu[4];                                                          \
      uu[0] = SU[(ng +  0) * 65 + k];                                       \
      uu[1] = SU[(ng + 32) * 65 + k];                                       \
      uu[2] = SU[(ng + 64) * 65 + k];                                       \
      uu[3] = SU[(ng + 96) * 65 + k];                                       \
      float4 w0 = *(const float4*)&SW[k * 64 + fg * 8];                     \
      float4 w1 = *(const float4*)&SW[k * 64 + fg * 8 + 4];                 \
      float wv[8] = {w0.x, w0.y, w0.z, w0.w, w1.x, w1.y, w1.z, w1.w};       \
      _Pragma("unroll") for (int i = 0; i < 4; ++i)                         \
        _Pragma("unroll") for (int j = 0; j < 8; ++j)                       \
          ACC[i][j] = fmaf(uu[i], wv[j], ACC[i][j]);                        \
    }                                                                       \
  }

// A <- relu(relu(A + B + ba) @ wb + bb) @ wn
__global__ __launch_bounds__(256) void k_layer(float* __restrict__ A,
                                               const float* __restrict__ B,
                                               const float* __restrict__ ba,
                                               const float* __restrict__ wb,
                                               const float* __restrict__ bb,
                                               const float* __restrict__ wn,
                                               int n) {
  __shared__ float su[128 * 65];
  __shared__ float sw[64 * 64];
  int t = threadIdx.x;
  int base = blockIdx.x * 128;
  // phase 0: u = relu(A + B + ba) -> su ; stage wb -> sw
#pragma unroll
  for (int i = 0; i < 8; ++i) {
    int flat = i * 256 + t;          // [0, 2048): node*16 + f4
    int node = flat >> 4, f4 = flat & 15;
    int g = base + node;
    float4 a = make_float4(0.f, 0.f, 0.f, 0.f), b = a;
    if (g < n) {
      a = *(const float4*)(A + (size_t)g * 64 + f4 * 4);
      b = *(const float4*)(B + (size_t)g * 64 + f4 * 4);
    }
    float4 bi = ((const float4*)ba)[f4];
    float* d = &su[node * 65 + f4 * 4];
    d[0] = fmaxf(a.x + b.x + bi.x, 0.f);
    d[1] = fmaxf(a.y + b.y + bi.y, 0.f);
    d[2] = fmaxf(a.z + b.z + bi.z, 0.f);
    d[3] = fmaxf(a.w + b.w + bi.w, 0.f);
  }
#pragma unroll
  for (int i = 0; i < 4; ++i) {
    int w4 = i * 256 + t;
    *(float4*)&sw[w4 * 4] = ((const float4*)wb)[w4];
  }
  __syncthreads();

  int ng = t & 31, fg = t >> 5;
  float acc[4][8];
#pragma unroll
  for (int i = 0; i < 4; ++i)
#pragma unroll
    for (int j = 0; j < 8; ++j) acc[i][j] = 0.f;
  GEMM_TILE(su, sw, acc)
  __syncthreads();

  // phase 2: v = relu(acc + bb) -> su ; restage wn -> sw
  float4 bb0 = ((const float4*)bb)[fg * 2];
  float4 bb1 = ((const float4*)bb)[fg * 2 + 1];
  float bv[8] = {bb0.x, bb0.y, bb0.z, bb0.w, bb1.x, bb1.y, bb1.z, bb1.w};
#pragma unroll
  for (int i = 0; i < 4; ++i)
#pragma unroll
    for (int j = 0; j < 8; ++j)
      su[(ng + 32 * i) * 65 + fg * 8 + j] = fmaxf(acc[i][j] + bv[j], 0.f);
#pragma unroll
  for (int i = 0; i < 4; ++i) {
    int w4 = i * 256 + t;
    *(float4*)&sw[w4 * 4] = ((const float4*)wn)[w4];
  }
  __syncthreads();

  float acc2[4][8];
#pragma unroll
  for (int i = 0; i < 4; ++i)
#pragma unroll
    for (int j = 0; j < 8; ++j) acc2[i][j] = 0.f;
  GEMM_TILE(su, sw, acc2)

#pragma unroll
  for (int i = 0; i < 4; ++i) {
    int g = base + ng + 32 * i;
    if (g < n) {
      *(float4*)(A + (size_t)g * 64 + fg * 8) =
          make_float4(acc2[i][0], acc2[i][1], acc2[i][2], acc2[i][3]);
      *(float4*)(A + (size_t)g * 64 + fg * 8 + 4) =
          make_float4(acc2[i][4], acc2[i][5], acc2[i][6], acc2[i][7]);
    }
  }
}

// A = x @ w0a  (K = 128, two 64-chunks)
__global__ __launch_bounds__(256) void k_in(const float* __restrict__ x,
                                            const float* __restrict__ w,
                                            float* __restrict__ A, int n) {
  __shared__ float su[128 * 65];
  __shared__ float sw[64 * 64];
  int t = threadIdx.x;
  int base = blockIdx.x * 128;
  int ng = t & 31, fg = t >> 5;
  float acc[4][8];
#pragma unroll
  for (int i = 0; i < 4; ++i)
#pragma unroll
    for (int j = 0; j < 8; ++j) acc[i][j] = 0.f;

  for (int c = 0; c < 2; ++c) {
#pragma unroll
    for (int i = 0; i < 8; ++i) {
      int flat = i * 256 + t;
      int node = flat >> 4, f4 = flat & 15;
      int g = base + node;
      float4 a = make_float4(0.f, 0.f, 0.f, 0.f);
      if (g < n) a = *(const float4*)(x + (size_t)g * 128 + c * 64 + f4 * 4);
      *(float4*)&su[node * 65 + f4 * 4] = a;  // stride 65: f4*4 slots 0..63 ok
    }
#pragma unroll
    for (int i = 0; i < 4; ++i) {
      int w4 = i * 256 + t;
      *(float4*)&sw[w4 * 4] = ((const float4*)(w + c * 64 * 64))[w4];
    }
    __syncthreads();
    GEMM_TILE(su, sw, acc)
    __syncthreads();
  }
#pragma unroll
  for (int i = 0; i < 4; ++i) {
    int g = base + ng + 32 * i;
    if (g < n) {
      *(float4*)(A + (size_t)g * 64 + fg * 8) =
          make_float4(acc[i][0], acc[i][1], acc[i][2], acc[i][3]);
      *(float4*)(A + (size_t)g * 64 + fg * 8 + 4) =
          make_float4(acc[i][4], acc[i][5], acc[i][6], acc[i][7]);
    }
  }
}

// h3 = relu(relu(A+B+ba)@wb+bb); pool per-graph sums into P.
__global__ __launch_bounds__(256) void k_final(const float* __restrict__ A,
                                               const float* __restrict__ B,
                                               const float* __restrict__ ba,
                                               const float* __restrict__ wb,
                                               const float* __restrict__ bb,
                                               const int* __restrict__ batch,
                                               float* __restrict__ P, int n) {
  __shared__ float su[128 * 65];
  __shared__ float sw[64 * 64];
  int t = threadIdx.x;
  int base = blockIdx.x * 128;
#pragma unroll
  for (int i = 0; i < 8; ++i) {
    int flat = i * 256 + t;
    int node = flat >> 4, f4 = flat & 15;
    int g = base + node;
    float4 a = make_float4(0.f, 0.f, 0.f, 0.f), b = a;
    if (g < n) {
      a = *(const float4*)(A + (size_t)g * 64 + f4 * 4);
      b = *(const float4*)(B + (size_t)g * 64 + f4 * 4);
    }
    float4 bi = ((const float4*)ba)[f4];
    float* d = &su[node * 65 + f4 * 4];
    d[0] = fmaxf(a.x + b.x + bi.x, 0.f);
    d[1] = fmaxf(a.y + b.y + bi.y, 0.f);
    d[2] = fmaxf(a.z + b.z + bi.z, 0.f);
    d[3] = fmaxf(a.w + b.w + bi.w, 0.f);
  }
#pragma unroll
  for (int i = 0; i < 4; ++i) {
    int w4 = i * 256 + t;
    *(float4*)&sw[w4 * 4] = ((const float4*)wb)[w4];
  }
  __syncthreads();

  int ng = t & 31, fg = t >> 5;
  float acc[4][8];
#pragma unroll
  for (int i = 0; i < 4; ++i)
#pragma unroll
    for (int j = 0; j < 8; ++j) acc[i][j] = 0.f;
  GEMM_TILE(su, sw, acc)
  __syncthreads();

  float4 bb0 = ((const float4*)bb)[fg * 2];
  float4 bb1 = ((const float4*)bb)[fg * 2 + 1];
  float bv[8] = {bb0.x, bb0.y, bb0.z, bb0.w, bb1.x, bb1.y, bb1.z, bb1.w};
#pragma unroll
  for (int i = 0; i < 4; ++i)
#pragma unroll
    for (int j = 0; j < 8; ++j)
      su[(ng + 32 * i) * 65 + fg * 8 + j] = fmaxf(acc[i][j] + bv[j], 0.f);
  __syncthreads();

  // pooling: thread (f = t&63, q = t>>6) scans 32 nodes; batch is sorted ->
  // run-length accumulate, one atomic per (graph, f) per strip.
  int f = t & 63, q = t >> 6;
  float run = 0.f;
  int cur = -1;
  for (int k = 0; k < 32; ++k) {
    int node = q * 32 + k;
    int g = base + node;
    int gr = (g < n) ? batch[g] : -1;  // wave-uniform
    float val = su[node * 65 + f];
    if (gr != cur) {
      if (cur >= 0) unsafeAtomicAdd(&P[(size_t)cur * 64 + f], run);
      run = 0.f;
      cur = gr;
    }
    run += val;
  }
  if (cur >= 0) unsafeAtomicAdd(&P[(size_t)cur * 64 + f], run);
}

__global__ __launch_bounds__(256) void k_head(const float* __restrict__ P,
                                              const float* __restrict__ w1,
                                              const float* __restrict__ b1,
                                              const float* __restrict__ w2,
                                              const float* __restrict__ b2,
                                              float* __restrict__ out, int ng) {
  int g = blockIdx.x * 256 + threadIdx.x;
  if (g >= ng) return;
  const float4* Pr = (const float4*)(P + (size_t)g * 64);
  float t[64];
#pragma unroll
  for (int j = 0; j < 64; ++j) t[j] = b1[j];
#pragma unroll
  for (int k4 = 0; k4 < 16; ++k4) {
    float4 a = Pr[k4];
#pragma unroll
    for (int kk = 0; kk < 4; ++kk) {
      float ps = (&a.x)[kk];
      const float* wr = w1 + (k4 * 4 + kk) * 64;
#pragma unroll
      for (int j = 0; j < 64; ++j) t[j] = fmaf(ps, wr[j], t[j]);
    }
  }
  float o = b2[0];
#pragma unroll
  for (int j = 0; j < 64; ++j) o = fmaf(fmaxf(t[j], 0.f), w2[j], o);
  out[g] = o;
}

extern "C" void kernel_launch(void* const* d_in, const int* in_sizes, int n_in,
                              void* d_out, int out_size, void* d_ws, size_t ws_size,
                              hipStream_t stream) {
  const float* x   = (const float*)d_in[0];
  const int*   ei  = (const int*)d_in[1];
  const int*   bat = (const int*)d_in[2];
  const float* w0a = (const float*)d_in[3];
  const float* b0a = (const float*)d_in[4];
  const float* w0b = (const float*)d_in[5];
  const float* b0b = (const float*)d_in[6];
  const float* w1a = (const float*)d_in[7];
  const float* b1a = (const float*)d_in[8];
  const float* w1b = (const float*)d_in[9];
  const float* b1b = (const float*)d_in[10];
  const float* w2a = (const float*)d_in[11];
  const float* b2a = (const float*)d_in[12];
  const float* w2b = (const float*)d_in[13];
  const float* b2b = (const float*)d_in[14];
  const float* wh1 = (const float*)d_in[15];
  const float* bh1 = (const float*)d_in[16];
  const float* wh2 = (const float*)d_in[17];
  const float* bh2 = (const float*)d_in[18];
  float* out = (float*)d_out;

  const int N = in_sizes[0] / 128;   // 500000
  const int E = in_sizes[1] / 2;     // 1250000
  const int G = out_size;            // 16384

  char* w = (char*)d_ws;
  float* A    = (float*)w;  w += (size_t)N * 64 * sizeof(float);   // 128 MB
  float* B    = (float*)w;  w += (size_t)N * 64 * sizeof(float);   // 128 MB
  float* P    = (float*)w;  w += (size_t)G * 64 * sizeof(float);   // 4 MB
  int*   deg  = (int*)w;    w += (size_t)N * sizeof(int);          // 2 MB
  int*   cur  = (int*)w;    w += (size_t)N * sizeof(int);          // 2 MB
  int*   rp   = (int*)w;    w += (size_t)(N + 1) * sizeof(int);    // 2 MB
  int*   bsum = (int*)w;    w += 1024 * sizeof(int);
  int*   boff = (int*)w;    w += 1024 * sizeof(int);
  int*   csr  = (int*)w;    w += (size_t)E * sizeof(int);          // 5 MB

  hipMemsetAsync(P, 0, (size_t)G * 64 * sizeof(float), stream);
  hipMemsetAsync(deg, 0, (size_t)N * sizeof(int), stream);
  hipMemsetAsync(cur, 0, (size_t)N * sizeof(int), stream);

  int nb = (N + 255) / 256;
  int nb2 = (N + 127) / 128;         // tiled-GEMM grid (3907)
  int ebs = (E + 255) / 256;
  int ngb = (int)(((long)N * 16 + 255) / 256);
  int gb = (G + 255) / 256;
  int nb1 = (N + 1023) / 1024;       // scan blocks (489)

  // CSR build (same every call; edges restored pristine before each launch)
  k_deg<<<ebs, 256, 0, stream>>>(ei, deg, E);
  k_scan1<<<nb1, 1024, 0, stream>>>(deg, rp, bsum, N);
  k_scan2<<<1, 512, 0, stream>>>(bsum, boff, nb1);
  k_scan3<<<nb, 256, 0, stream>>>(rp, boff, N);
  k_fill<<<ebs, 256, 0, stream>>>(ei, rp, cur, csr, E);

  k_in<<<nb2, 256, 0, stream>>>(x, w0a, A, N);
  k_gather<<<ngb, 256, 0, stream>>>(rp, deg, csr, A, B, N);
  k_layer<<<nb2, 256, 0, stream>>>(A, B, b0a, w0b, b0b, w1a, N);
  k_gather<<<ngb, 256, 0, stream>>>(rp, deg, csr, A, B, N);
  k_layer<<<nb2, 256, 0, stream>>>(A, B, b1a, w1b, b1b, w2a, N);
  k_gather<<<ngb, 256, 0, stream>>>(rp, deg, csr, A, B, N);
  k_final<<<nb2, 256, 0, stream>>>(A, B, b2a, w2b, b2b, bat, P, N);
  k_head<<<gb, 256, 0, stream>>>(P, wh1, bh1, wh2, bh2, out, G);
}